// Round 2
// baseline (262.384 us; speedup 1.0000x reference)
//
#include <hip/hip_runtime.h>
#include <math.h>

#define N_NODES 8192
#define D_FEAT  512
#define DEG     16
#define E_EDGES (N_NODES * DEG)
#define FEAT_W  576      // 544 used (8*(64+4)) + 32 zero-pad for K%64==0
#define FEAT_USED 544
#define OUT_W   512
#define QKV_W   1664     // 512 q | 512 k | 512 v | 24 qv | 104 pad  (13*128)
#define BF_ROWS 1792     // Bfuse padded (zeros beyond 1560)

typedef unsigned short u16;
typedef __attribute__((ext_vector_type(8))) short short8;   // 8 bf16 for MFMA
typedef __attribute__((ext_vector_type(8))) unsigned short us8;
typedef __attribute__((ext_vector_type(4))) float f32x4;

// ---- bf16 helpers (RNE) ----------------------------------------------------
__device__ __forceinline__ u16 f2bf(float f) {
    union { float f; unsigned u; } c; c.f = f;
    unsigned u = c.u;
    unsigned r = u + 0x7FFFu + ((u >> 16) & 1u);
    return (u16)(r >> 16);
}
__device__ __forceinline__ float bf2f(u16 h) {
    union { unsigned u; float f; } c; c.u = ((unsigned)h) << 16;
    return c.f;
}

// ---- async global->LDS 16B (lds dest = wave-uniform base + lane*16) --------
__device__ __forceinline__ void async16(const void* g, void* l) {
    __builtin_amdgcn_global_load_lds(
        (const __attribute__((address_space(1))) void*)g,
        (__attribute__((address_space(3))) void*)l, 16, 0, 0);
}

// ---------------------------------------------------------------------------
// qkv GEMM, register-resident-B streaming design (round-2 pivot):
//   qkv[8192, 1600 used] = xh[8192,512] * Bfuse[.,512]^T
// Rationale: K=512 -> a wave's 16-col B-slice over full K is 16 short8 = 64
// VGPRs. Hold B in registers, stream A fragments straight from global
// (A[lrow][ks*32+quad*8] is one 64B line per row -> coalesced), run ZERO
// barriers / ZERO LDS. Compiler vmcnt pipelining handles overlap (m97/m114).
// Block = 4 waves = 64 cols x 256 rows. Grid 800 = 32 m x 25 n (the
// 1600-1663 pad tile is skipped entirely), XCD-swizzled so each XCD's 100
// blocks share a 1MB A-slice (L2-resident). Even/odd accumulators break the
// 16-deep MFMA dependence chain.
// ---------------------------------------------------------------------------
__global__ __launch_bounds__(256) void gemm_qkv(
    const u16* __restrict__ xh, const u16* __restrict__ Bfuse,
    u16* __restrict__ qkv)
{
    const int tid  = threadIdx.x;
    const int wave = tid >> 6;          // 0..3 -> which 16-col slice
    const int lane = tid & 63;
    const int lrow = lane & 15;
    const int quad = lane >> 4;

    // grid 800 = 8 XCD x 100; per XCD: 4 m-groups x 25 n-tiles
    const int flat = blockIdx.x;
    const int xcd  = flat & 7;
    const int rr   = flat >> 3;                 // 0..99
    const int bm   = (xcd * 4 + rr / 25) * 256;
    const int bn   = (rr % 25) * 64;

    // ---- B slice into registers: 16 k-slices of short8 (64 VGPRs) ----------
    const int coln = bn + wave * 16 + lrow;     // output column, < 1600
    short8 b[16];
    {
        const u16* gB = Bfuse + (size_t)coln * 512 + quad * 8;
        #pragma unroll
        for (int ks = 0; ks < 16; ++ks)
            b[ks] = *(const short8*)(gB + ks * 32);
    }

    const u16* gA = xh + (size_t)(bm + lrow) * 512 + quad * 8;
    u16* gC = qkv + (size_t)(bm + quad * 4) * QKV_W + coln;
    const bool wr_ok = (coln < 1560);

    #pragma unroll 2
    for (int mt = 0; mt < 16; ++mt) {           // 16 m-tiles of 16 rows
        const u16* ga = gA + (size_t)(mt * 16) * 512;
        short8 a[16];
        #pragma unroll
        for (int ks = 0; ks < 16; ++ks)
            a[ks] = *(const short8*)(ga + ks * 32);

        f32x4 ae = {0.f, 0.f, 0.f, 0.f};
        f32x4 ao = {0.f, 0.f, 0.f, 0.f};
        #pragma unroll
        for (int ks = 0; ks < 16; ks += 2) {
            ae = __builtin_amdgcn_mfma_f32_16x16x32_bf16(a[ks],     b[ks],     ae, 0, 0, 0);
            ao = __builtin_amdgcn_mfma_f32_16x16x32_bf16(a[ks + 1], b[ks + 1], ao, 0, 0, 0);
        }

        if (wr_ok) {
            u16* gc = gC + (size_t)(mt * 16) * QKV_W;
            #pragma unroll
            for (int r = 0; r < 4; ++r)
                gc[(size_t)r * QKV_W] = f2bf(ae[r] + ao[r]);
        }
    }
}

// ---------------------------------------------------------------------------
// Out GEMM: out[8192,512] = feat[8192,576] * Woth[512,576]^T + bout.
// 64x128 tiles, BK=64, grid 512 = 2 blocks/CU. R11-proven.
// ---------------------------------------------------------------------------
__global__ __launch_bounds__(256) void gemm_out(
    const u16* __restrict__ feat, const u16* __restrict__ Woth,
    const float* __restrict__ bout, float* __restrict__ out)
{
    __shared__ u16 smem[64 * 64 + 128 * 64];   // 24 KB
    u16* sA = smem;
    u16* sB = smem + 64 * 64;

    const int tid = threadIdx.x;
    const int flat = blockIdx.x;
    const int xcd = flat & 7;
    const int rr  = flat >> 3;                  // 0..63
    const int bm  = (xcd + 8 * (rr / 4)) * 64;
    const int bn  = (rr % 4) * 128;

    const int wave = tid >> 6;
    const int lane = tid & 63;
    const int wr   = (wave >> 1) * 32;
    const int wc   = (wave & 1) * 64;
    const int lrow = lane & 15;
    const int quad = lane >> 4;

    f32x4 acc[2][4];
    #pragma unroll
    for (int i = 0; i < 2; ++i)
        #pragma unroll
        for (int j = 0; j < 4; ++j) {
            f32x4 z = {0.f, 0.f, 0.f, 0.f};
            acc[i][j] = z;
        }

    for (int k0 = 0; k0 < FEAT_W; k0 += 64) {
        #pragma unroll
        for (int i = 0; i < 2; ++i) {             // A: 512 chunks
            const int lin = i * 256 + tid;
            const int row = lin >> 3;
            const int seg = ((lin & 7) ^ (row & 7)) << 3;
            async16(feat + (size_t)(bm + row) * FEAT_W + k0 + seg, sA + (lin << 3));
        }
        #pragma unroll
        for (int i = 0; i < 4; ++i) {             // B: 1024 chunks
            const int lin = i * 256 + tid;
            const int row = lin >> 3;
            const int seg = ((lin & 7) ^ (row & 7)) << 3;
            async16(Woth + (size_t)(bn + row) * FEAT_W + k0 + seg, sB + (lin << 3));
        }
        __syncthreads();

        #pragma unroll
        for (int ko = 0; ko < 64; ko += 32) {
            const int cbase = ko >> 3;
            short8 a_h[2], b_h[4];
            #pragma unroll
            for (int t = 0; t < 2; ++t) {
                const int ra = wr + t * 16 + lrow;
                a_h[t] = *(const short8*)&sA[ra * 64 + (((cbase + quad) ^ (ra & 7)) << 3)];
            }
            #pragma unroll
            for (int t = 0; t < 4; ++t) {
                const int rb = wc + t * 16 + lrow;
                b_h[t] = *(const short8*)&sB[rb * 64 + (((cbase + quad) ^ (rb & 7)) << 3)];
            }
            #pragma unroll
            for (int mt = 0; mt < 2; ++mt)
                #pragma unroll
                for (int nt = 0; nt < 4; ++nt)
                    acc[mt][nt] = __builtin_amdgcn_mfma_f32_16x16x32_bf16(
                        a_h[mt], b_h[nt], acc[mt][nt], 0, 0, 0);
        }
        __syncthreads();
    }

    #pragma unroll
    for (int nt = 0; nt < 4; ++nt) {
        const int col = bn + wc + nt * 16 + lrow;
        const float bb = bout[col];
        #pragma unroll
        for (int mt = 0; mt < 2; ++mt)
            #pragma unroll
            for (int r = 0; r < 4; ++r) {
                const int row = bm + wr + mt * 16 + quad * 4 + r;
                out[(size_t)row * OUT_W + col] = acc[mt][nt][r] + bb;
            }
    }
}

// ---------------------------------------------------------------------------
// Fused prep: x->bf16, Bfuse (1792 rows incl. qv + zero pad), Woth.
// ---------------------------------------------------------------------------
__global__ __launch_bounds__(256) void prep_kernel(
    const float* __restrict__ x,
    const float* __restrict__ Wq, const float* __restrict__ Wk,
    const float* __restrict__ Wv, const float* __restrict__ Wqv,
    const float* __restrict__ Wout,
    u16* __restrict__ xh, u16* __restrict__ B, u16* __restrict__ Woth)
{
    const int b = blockIdx.x;
    const int tid = threadIdx.x;
    if (b < 4096) {
        const int i = b * 256 + tid;
        const float4 v = ((const float4*)x)[i];
        ushort4 h;
        h.x = f2bf(v.x); h.y = f2bf(v.y); h.z = f2bf(v.z); h.w = f2bf(v.w);
        ((ushort4*)xh)[i] = h;
    } else if (b < 4992) {
        const int idx = (b - 4096) * 256 + tid;      // < 229376 = 1792*128
        const int row = idx >> 7;                    // 0..1791
        const int c4  = idx & 127;
        float4 v = make_float4(0.f, 0.f, 0.f, 0.f);
        float scale = 1.f;
        if (row < 512) {
            v = *(const float4*)(Wq + (size_t)row * 512 + c4 * 4);
            scale = 0.125f;                          // 1/sqrt(64) folded into Wq
        } else if (row < 1024) {
            v = *(const float4*)(Wk + (size_t)(row - 512) * 512 + c4 * 4);
        } else if (row < 1536) {
            v = *(const float4*)(Wv + (size_t)(row - 1024) * 512 + c4 * 4);
        } else if (row < 1560) {
            v = *(const float4*)(Wqv + (size_t)(row - 1536) * 512 + c4 * 4);
        }
        ushort4 h;
        h.x = f2bf(v.x * scale); h.y = f2bf(v.y * scale);
        h.z = f2bf(v.z * scale); h.w = f2bf(v.w * scale);
        ((ushort4*)B)[idx] = h;
    } else {
        const int i = (b - 4992) * 256 + tid;        // < 73728 exact
        const int row = i / (FEAT_W / 4);            // /144
        const int c4  = i % (FEAT_W / 4);
        float4 v = make_float4(0.f, 0.f, 0.f, 0.f);
        if (c4 < FEAT_USED / 4)
            v = *(const float4*)(Wout + (size_t)row * FEAT_USED + c4 * 4);
        ushort4 h;
        h.x = f2bf(v.x); h.y = f2bf(v.y); h.z = f2bf(v.z); h.w = f2bf(v.w);
        ((ushort4*)Woth)[i] = h;
    }
}

// ---------------------------------------------------------------------------
// Edge stage: TWO WAVES PER NODE (wave owns 8 edges, all 512 dims).
// Block = 256 threads = 4 waves = 2 nodes. lane = h*8+sub; hoff = lane*8.
// Pass 1: each wave computes 8 logits (coalesced k-row gathers).
// LDS exchange of per-head logits (64 fp32/node) -> full 16-way softmax
// replicated in both waves. Pass 2: each wave re-gathers its 8 v rows and
// accumulates partial y/dx/dy/dz/aid; wave 0 publishes partials via LDS;
// wave 1 combines and writes feat. ~6 KB LDS/block -> occupancy VGPR-bound.
// ---------------------------------------------------------------------------
__global__ __launch_bounds__(256) void edge_kernel(
    const u16* __restrict__ qkv,        // [N, 1664] bf16
    const int* __restrict__ col_index, const int* __restrict__ to_col,
    const float* __restrict__ att_bias, const float* __restrict__ dist,
    const float* __restrict__ pos, const float* __restrict__ col_pos,
    u16* __restrict__ feat)             // [N, 576] bf16 (544 used)
{
    __shared__ float sLog[2][2][8][8];  // [node][wave][head][edge]  2 KB
    __shared__ float sY[2][512];        // partial y exchange        4 KB
    __shared__ float sV[2][8][4];       // dx,dy,dz,aid per head     256 B

    const int wave4 = threadIdx.x >> 6;   // 0..3
    const int nb = wave4 >> 1;            // node within block
    const int w  = wave4 & 1;             // wave within node
    const int lane = threadIdx.x & 63;
    const int n = blockIdx.x * 2 + nb;
    const int h = lane >> 3;
    const int sub = lane & 7;
    const int hoff = lane * 8;            // == h*64 + sub*8

    const size_t qbase = (size_t)n * QKV_W;

    // q fragment (8 dims), fp32
    float qf[8];
    {
        const us8 qu = *(const us8*)(qkv + qbase + hoff);
        #pragma unroll
        for (int i = 0; i < 8; ++i) qf[i] = bf2f(qu[i]);
    }
    // qv (3 per head) via wave shuffle from the 24 bf16 at col 1536
    float qv0, qv1, qv2;
    {
        const float qvl = bf2f(qkv[qbase + 1536 + (lane < 24 ? lane : 0)]);
        qv0 = __shfl(qvl, h * 3 + 0);
        qv1 = __shfl(qvl, h * 3 + 1);
        qv2 = __shfl(qvl, h * 3 + 2);
    }
    const float px = pos[3 * n + 0], py = pos[3 * n + 1], pz = pos[3 * n + 2];

    // per-edge metadata for THIS wave's 8 edges, held in lanes 0..7
    // (all 8-lane groups hold duplicates)
    const int j8 = lane & 7;
    const int e0 = n * DEG + w * 8 + j8;
    const int c_l  = col_index[e0];
    const int cc_l = to_col[c_l];
    const float d_l = dist[e0];
    const float invd_l = (d_l == 0.f) ? 0.f : (1.f / d_l);
    const float rx_l = col_pos[3 * c_l + 0] - px;
    const float ry_l = col_pos[3 * c_l + 1] - py;
    const float rz_l = col_pos[3 * c_l + 2] - pz;

    // bias: lane (h,sub) holds bias for head h, edge w*8+sub
    const float b_own = att_bias[(size_t)h * E_EDGES + n * DEG + w * 8 + sub];

    // ---- pass 1: logits for my 8 edges -------------------------------------
    float logit[8];
    #pragma unroll
    for (int j = 0; j < 8; ++j) {
        const int cc = __shfl(cc_l, j);
        const us8 ku = *(const us8*)(qkv + (size_t)cc * QKV_W + 512 + hoff);
        float dot = 0.f;
        #pragma unroll
        for (int i = 0; i < 8; ++i) dot += qf[i] * bf2f(ku[i]);
        dot += __shfl_xor(dot, 1, 8);
        dot += __shfl_xor(dot, 2, 8);
        dot += __shfl_xor(dot, 4, 8);
        const float invd = __shfl(invd_l, j);
        const float ang = qv0 * __shfl(rx_l, j) + qv1 * __shfl(ry_l, j)
                        + qv2 * __shfl(rz_l, j);
        const float bj = __shfl(b_own, j, 8);   // lane h*8+j of this group
        logit[j] = dot + bj + ang * invd;
    }

    // ---- exchange logits, softmax over all 16 ------------------------------
    if (sub == 0) {
        #pragma unroll
        for (int j = 0; j < 8; ++j) sLog[nb][w][h][j] = logit[j];
    }
    __syncthreads();
    float lo[8];
    #pragma unroll
    for (int j = 0; j < 8; ++j) lo[j] = sLog[nb][1 - w][h][j];

    float m = logit[0];
    #pragma unroll
    for (int j = 1; j < 8; ++j) m = fmaxf(m, logit[j]);
    #pragma unroll
    for (int j = 0; j < 8; ++j) m = fmaxf(m, lo[j]);
    float s = 0.f;
    #pragma unroll
    for (int j = 0; j < 8; ++j) { logit[j] = __expf(logit[j] - m); s += logit[j]; }
    #pragma unroll
    for (int j = 0; j < 8; ++j) s += __expf(lo[j] - m);
    const float inv_s = 1.f / s;

    // ---- pass 2: weighted accumulation over my 8 edges ---------------------
    float y[8] = {0.f, 0.f, 0.f, 0.f, 0.f, 0.f, 0.f, 0.f};
    float dx = 0.f, dy = 0.f, dz = 0.f, aid = 0.f;
    #pragma unroll
    for (int j = 0; j < 8; ++j) {
        const float a = logit[j] * inv_s;
        const int cc = __shfl(cc_l, j);
        const us8 vu = *(const us8*)(qkv + (size_t)cc * QKV_W + 1024 + hoff);
        #pragma unroll
        for (int i = 0; i < 8; ++i) y[i] += a * bf2f(vu[i]);
        const float na = a * __shfl(invd_l, j);
        dx += na * __shfl(rx_l, j);      // dst_vec - src_vec == sum na*rel
        dy += na * __shfl(ry_l, j);
        dz += na * __shfl(rz_l, j);
        aid += na;
    }

    // ---- combine the two waves' partials -----------------------------------
    if (w == 0) {
        #pragma unroll
        for (int i = 0; i < 8; ++i) sY[nb][hoff + i] = y[i];
        if (sub == 0) {
            sV[nb][h][0] = dx; sV[nb][h][1] = dy;
            sV[nb][h][2] = dz; sV[nb][h][3] = aid;
        }
    }
    __syncthreads();
    if (w == 1) {
        #pragma unroll
        for (int i = 0; i < 8; ++i) y[i] += sY[nb][hoff + i];

        u16* f = feat + (size_t)n * FEAT_W + h * 68;
        ushort4 o0, o1;
        o0.x = f2bf(y[0]); o0.y = f2bf(y[1]); o0.z = f2bf(y[2]); o0.w = f2bf(y[3]);
        o1.x = f2bf(y[4]); o1.y = f2bf(y[5]); o1.z = f2bf(y[6]); o1.w = f2bf(y[7]);
        *(ushort4*)(f + sub * 8 + 0) = o0;
        *(ushort4*)(f + sub * 8 + 4) = o1;
        if (sub == 0) {
            dx += sV[nb][h][0]; dy += sV[nb][h][1];
            dz += sV[nb][h][2]; aid += sV[nb][h][3];
            const float nrm = sqrtf(dx * dx + dy * dy + dz * dz);
            const float rn = 1.f / fmaxf(nrm, 1e-12f);
            ushort4 ex;
            ex.x = f2bf(dx * rn); ex.y = f2bf(dy * rn);
            ex.z = f2bf(dz * rn); ex.w = f2bf(aid);
            *(ushort4*)(f + 64) = ex;
        }
    }
}

// ---------------------------------------------------------------------------
extern "C" void kernel_launch(void* const* d_in, const int* in_sizes, int n_in,
                              void* d_out, int out_size, void* d_ws, size_t ws_size,
                              hipStream_t stream)
{
    const float* x         = (const float*)d_in[0];
    const int*   col_index = (const int*)d_in[2];
    const int*   to_col    = (const int*)d_in[3];
    const float* att_bias  = (const float*)d_in[4];
    const float* dist      = (const float*)d_in[5];
    const float* pos       = (const float*)d_in[6];
    const float* col_pos   = (const float*)d_in[7];
    const float* Wq        = (const float*)d_in[8];
    const float* Wqv       = (const float*)d_in[9];
    const float* Wk        = (const float*)d_in[10];
    const float* Wv        = (const float*)d_in[11];
    const float* Wout      = (const float*)d_in[12];
    const float* bout      = (const float*)d_in[13];
    float* out = (float*)d_out;

    // Workspace layout (bytes), total ~47.5 MB
    char* ws = (char*)d_ws;
    u16* qkv   = (u16*)(ws + 0);           // [8192,1664] bf16  27,262,976
    u16* xh    = (u16*)(ws + 27262976);    // [8192,512]  bf16   8,388,608
    u16* Bfuse = (u16*)(ws + 35651584);    // [1792,512]  bf16   1,835,008
    u16* Woth  = (u16*)(ws + 37486592);    // [512,576]   bf16     589,824
    u16* feat  = (u16*)(ws + 38076416);    // [8192,576]  bf16   9,437,184

    dim3 blk(256);

    // 0) prep: x->bf16, Bfuse (incl. qv rows + zero pad to 1792), Woth
    hipLaunchKernelGGL(prep_kernel, dim3(5280), blk, 0, stream,
                       x, Wq, Wk, Wv, Wqv, Wout, xh, Bfuse, Woth);

    // 1) qkv = xh * Bfuse^T  (800 blocks, reg-B streaming, no LDS/barriers)
    hipLaunchKernelGGL(gemm_qkv, dim3(800), blk, 0, stream, xh, Bfuse, qkv);

    // 2) edge: 2 waves per node, LDS logit/partial exchange
    hipLaunchKernelGGL(edge_kernel, dim3(N_NODES / 2), blk, 0, stream,
                       qkv, col_index, to_col, att_bias, dist, pos, col_pos, feat);

    // 3) out = feat * Woth^T + bout  (64x128 tiles, grid 512 = 2/CU)
    hipLaunchKernelGGL(gemm_out, dim3(512), blk, 0, stream,
                       feat, Woth, bout, out);
}

// Round 3
// 251.929 us; speedup vs baseline: 1.0415x; 1.0415x over previous
//
#include <hip/hip_runtime.h>
#include <math.h>

#define N_NODES 8192
#define D_FEAT  512
#define DEG     16
#define E_EDGES (N_NODES * DEG)
#define FEAT_W  576      // 544 used (8*(64+4)) + 32 zero-pad for K%64==0
#define FEAT_USED 544
#define OUT_W   512
#define QKV_W   1664     // 512 q | 512 k | 512 v | 24 qv | 104 pad  (13*128)
#define BF_ROWS 1792     // Bfuse padded (zeros beyond 1560)

typedef unsigned short u16;
typedef __attribute__((ext_vector_type(8))) short short8;   // 8 bf16 for MFMA
typedef __attribute__((ext_vector_type(8))) unsigned short us8;
typedef __attribute__((ext_vector_type(4))) float f32x4;

// ---- bf16 helpers (RNE) ----------------------------------------------------
__device__ __forceinline__ u16 f2bf(float f) {
    union { float f; unsigned u; } c; c.f = f;
    unsigned u = c.u;
    unsigned r = u + 0x7FFFu + ((u >> 16) & 1u);
    return (u16)(r >> 16);
}
__device__ __forceinline__ float bf2f(u16 h) {
    union { unsigned u; float f; } c; c.u = ((unsigned)h) << 16;
    return c.f;
}

// ---- async global->LDS 16B (lds dest = wave-uniform base + lane*16) --------
__device__ __forceinline__ void async16(const void* g, void* l) {
    __builtin_amdgcn_global_load_lds(
        (const __attribute__((address_space(1))) void*)g,
        (__attribute__((address_space(3))) void*)l, 16, 0, 0);
}

// ---------------------------------------------------------------------------
// qkv GEMM, register-resident-B streaming, round-3 fix:
// Round 2's version compiled to VGPR=44 -- the compiler rematerialized the
// B slice (reloaded from L2 every m-tile) and broke the A-tile array into
// load-use pairs (zero prefetch depth) -> latency-serial, 127us. Fix: PIN
// the registers with empty inline asm ("+v") so b[16] is genuinely resident
// (64 VGPRs) and each A buffer's 16 loads are forced simultaneously in
// flight. Double-buffered A (a0/a1), fully static indexing, no LDS, no
// barriers. Block = 4 waves = 64 cols x 128 rows. Grid 1600 = 64 m x 25 n,
// XCD-grouped (1MB A-slice per XCD L2, reused 25x).
// ---------------------------------------------------------------------------
__global__ __launch_bounds__(256, 2) void gemm_qkv(
    const u16* __restrict__ xh, const u16* __restrict__ Bfuse,
    u16* __restrict__ qkv)
{
    const int tid  = threadIdx.x;
    const int wave = tid >> 6;          // 0..3 -> which 16-col slice
    const int lane = tid & 63;
    const int lrow = lane & 15;
    const int quad = lane >> 4;

    // grid 1600 = 8 XCD x 200; per XCD: 8 m-groups (128 rows) x 25 n-tiles
    const int flat = blockIdx.x;
    const int xcd  = flat & 7;
    const int rr   = flat >> 3;                 // 0..199
    const int bm   = (xcd * 8 + rr / 25) * 128;
    const int bn   = (rr % 25) * 64;

    // ---- B slice into registers: 16 k-slices of short8 (64 VGPRs), pinned --
    const int coln = bn + wave * 16 + lrow;     // output column, < 1600
    short8 b[16];
    {
        const u16* gB = Bfuse + (size_t)coln * 512 + quad * 8;
        #pragma unroll
        for (int ks = 0; ks < 16; ++ks)
            b[ks] = *(const short8*)(gB + ks * 32);
    }
    #pragma unroll
    for (int ks = 0; ks < 16; ++ks)
        asm volatile("" : "+v"(b[ks]));         // forbid rematerialization

    const u16* gA = xh + (size_t)(bm + lrow) * 512 + quad * 8;
    u16* gC = qkv + (size_t)(bm + quad * 4) * QKV_W + coln;
    const bool wr_ok = (coln < 1560);

#define LOAD_A(dst, mt) do {                                                 \
        const u16* _ga = gA + (size_t)((mt) * 16) * 512;                     \
        _Pragma("unroll")                                                    \
        for (int ks = 0; ks < 16; ++ks)                                      \
            dst[ks] = *(const short8*)(_ga + ks * 32);                       \
    } while (0)

#define PIN_A(dst) do {                                                      \
        _Pragma("unroll")                                                    \
        for (int ks = 0; ks < 16; ++ks) asm volatile("" : "+v"(dst[ks]));    \
    } while (0)

#define COMP_ST(buf, mt) do {                                                \
        f32x4 ae = {0.f, 0.f, 0.f, 0.f};                                     \
        f32x4 ao = {0.f, 0.f, 0.f, 0.f};                                     \
        _Pragma("unroll")                                                    \
        for (int ks = 0; ks < 16; ks += 2) {                                 \
            ae = __builtin_amdgcn_mfma_f32_16x16x32_bf16(buf[ks],     b[ks],     ae, 0, 0, 0); \
            ao = __builtin_amdgcn_mfma_f32_16x16x32_bf16(buf[ks + 1], b[ks + 1], ao, 0, 0, 0); \
        }                                                                    \
        if (wr_ok) {                                                         \
            u16* _gc = gC + (size_t)((mt) * 16) * QKV_W;                     \
            _Pragma("unroll")                                                \
            for (int r = 0; r < 4; ++r)                                      \
                _gc[(size_t)r * QKV_W] = f2bf(ae[r] + ao[r]);                \
        }                                                                    \
    } while (0)

    short8 a0[16], a1[16];
    LOAD_A(a0, 0);
    LOAD_A(a1, 1);

    #pragma unroll
    for (int m2 = 0; m2 < 4; ++m2) {            // 8 m-tiles of 16 rows
        PIN_A(a0);                              // single wait point for a0
        COMP_ST(a0, 2 * m2);
        if (m2 < 3) LOAD_A(a0, 2 * m2 + 2);     // in flight during a1 compute
        PIN_A(a1);
        COMP_ST(a1, 2 * m2 + 1);
        if (m2 < 3) LOAD_A(a1, 2 * m2 + 3);     // in flight during a0 compute
    }
#undef LOAD_A
#undef PIN_A
#undef COMP_ST
}

// ---------------------------------------------------------------------------
// Out GEMM: out[8192,512] = feat[8192,576] * Woth[512,576]^T + bout.
// 64x128 tiles, BK=64, grid 512 = 2 blocks/CU. R11-proven.
// ---------------------------------------------------------------------------
__global__ __launch_bounds__(256) void gemm_out(
    const u16* __restrict__ feat, const u16* __restrict__ Woth,
    const float* __restrict__ bout, float* __restrict__ out)
{
    __shared__ u16 smem[64 * 64 + 128 * 64];   // 24 KB
    u16* sA = smem;
    u16* sB = smem + 64 * 64;

    const int tid = threadIdx.x;
    const int flat = blockIdx.x;
    const int xcd = flat & 7;
    const int rr  = flat >> 3;                  // 0..63
    const int bm  = (xcd + 8 * (rr / 4)) * 64;
    const int bn  = (rr % 4) * 128;

    const int wave = tid >> 6;
    const int lane = tid & 63;
    const int wr   = (wave >> 1) * 32;
    const int wc   = (wave & 1) * 64;
    const int lrow = lane & 15;
    const int quad = lane >> 4;

    f32x4 acc[2][4];
    #pragma unroll
    for (int i = 0; i < 2; ++i)
        #pragma unroll
        for (int j = 0; j < 4; ++j) {
            f32x4 z = {0.f, 0.f, 0.f, 0.f};
            acc[i][j] = z;
        }

    for (int k0 = 0; k0 < FEAT_W; k0 += 64) {
        #pragma unroll
        for (int i = 0; i < 2; ++i) {             // A: 512 chunks
            const int lin = i * 256 + tid;
            const int row = lin >> 3;
            const int seg = ((lin & 7) ^ (row & 7)) << 3;
            async16(feat + (size_t)(bm + row) * FEAT_W + k0 + seg, sA + (lin << 3));
        }
        #pragma unroll
        for (int i = 0; i < 4; ++i) {             // B: 1024 chunks
            const int lin = i * 256 + tid;
            const int row = lin >> 3;
            const int seg = ((lin & 7) ^ (row & 7)) << 3;
            async16(Woth + (size_t)(bn + row) * FEAT_W + k0 + seg, sB + (lin << 3));
        }
        __syncthreads();

        #pragma unroll
        for (int ko = 0; ko < 64; ko += 32) {
            const int cbase = ko >> 3;
            short8 a_h[2], b_h[4];
            #pragma unroll
            for (int t = 0; t < 2; ++t) {
                const int ra = wr + t * 16 + lrow;
                a_h[t] = *(const short8*)&sA[ra * 64 + (((cbase + quad) ^ (ra & 7)) << 3)];
            }
            #pragma unroll
            for (int t = 0; t < 4; ++t) {
                const int rb = wc + t * 16 + lrow;
                b_h[t] = *(const short8*)&sB[rb * 64 + (((cbase + quad) ^ (rb & 7)) << 3)];
            }
            #pragma unroll
            for (int mt = 0; mt < 2; ++mt)
                #pragma unroll
                for (int nt = 0; nt < 4; ++nt)
                    acc[mt][nt] = __builtin_amdgcn_mfma_f32_16x16x32_bf16(
                        a_h[mt], b_h[nt], acc[mt][nt], 0, 0, 0);
        }
        __syncthreads();
    }

    #pragma unroll
    for (int nt = 0; nt < 4; ++nt) {
        const int col = bn + wc + nt * 16 + lrow;
        const float bb = bout[col];
        #pragma unroll
        for (int mt = 0; mt < 2; ++mt)
            #pragma unroll
            for (int r = 0; r < 4; ++r) {
                const int row = bm + wr + mt * 16 + quad * 4 + r;
                out[(size_t)row * OUT_W + col] = acc[mt][nt][r] + bb;
            }
    }
}

// ---------------------------------------------------------------------------
// Fused prep: x->bf16, Bfuse (1792 rows incl. qv + zero pad), Woth.
// ---------------------------------------------------------------------------
__global__ __launch_bounds__(256) void prep_kernel(
    const float* __restrict__ x,
    const float* __restrict__ Wq, const float* __restrict__ Wk,
    const float* __restrict__ Wv, const float* __restrict__ Wqv,
    const float* __restrict__ Wout,
    u16* __restrict__ xh, u16* __restrict__ B, u16* __restrict__ Woth)
{
    const int b = blockIdx.x;
    const int tid = threadIdx.x;
    if (b < 4096) {
        const int i = b * 256 + tid;
        const float4 v = ((const float4*)x)[i];
        ushort4 h;
        h.x = f2bf(v.x); h.y = f2bf(v.y); h.z = f2bf(v.z); h.w = f2bf(v.w);
        ((ushort4*)xh)[i] = h;
    } else if (b < 4992) {
        const int idx = (b - 4096) * 256 + tid;      // < 229376 = 1792*128
        const int row = idx >> 7;                    // 0..1791
        const int c4  = idx & 127;
        float4 v = make_float4(0.f, 0.f, 0.f, 0.f);
        float scale = 1.f;
        if (row < 512) {
            v = *(const float4*)(Wq + (size_t)row * 512 + c4 * 4);
            scale = 0.125f;                          // 1/sqrt(64) folded into Wq
        } else if (row < 1024) {
            v = *(const float4*)(Wk + (size_t)(row - 512) * 512 + c4 * 4);
        } else if (row < 1536) {
            v = *(const float4*)(Wv + (size_t)(row - 1024) * 512 + c4 * 4);
        } else if (row < 1560) {
            v = *(const float4*)(Wqv + (size_t)(row - 1536) * 512 + c4 * 4);
        }
        ushort4 h;
        h.x = f2bf(v.x * scale); h.y = f2bf(v.y * scale);
        h.z = f2bf(v.z * scale); h.w = f2bf(v.w * scale);
        ((ushort4*)B)[idx] = h;
    } else {
        const int i = (b - 4992) * 256 + tid;        // < 73728 exact
        const int row = i / (FEAT_W / 4);            // /144
        const int c4  = i % (FEAT_W / 4);
        float4 v = make_float4(0.f, 0.f, 0.f, 0.f);
        if (c4 < FEAT_USED / 4)
            v = *(const float4*)(Wout + (size_t)row * FEAT_USED + c4 * 4);
        ushort4 h;
        h.x = f2bf(v.x); h.y = f2bf(v.y); h.z = f2bf(v.z); h.w = f2bf(v.w);
        ((ushort4*)Woth)[i] = h;
    }
}

// ---------------------------------------------------------------------------
// Edge stage: TWO WAVES PER NODE (wave owns 8 edges, all 512 dims).
// Block = 256 threads = 4 waves = 2 nodes. lane = h*8+sub; hoff = lane*8.
// Pass 1: each wave computes 8 logits (coalesced k-row gathers).
// LDS exchange of per-head logits (64 fp32/node) -> full 16-way softmax
// replicated in both waves. Pass 2: each wave re-gathers its 8 v rows and
// accumulates partial y/dx/dy/dz/aid; wave 0 publishes partials via LDS;
// wave 1 combines and writes feat. ~6 KB LDS/block -> occupancy VGPR-bound.
// ---------------------------------------------------------------------------
__global__ __launch_bounds__(256) void edge_kernel(
    const u16* __restrict__ qkv,        // [N, 1664] bf16
    const int* __restrict__ col_index, const int* __restrict__ to_col,
    const float* __restrict__ att_bias, const float* __restrict__ dist,
    const float* __restrict__ pos, const float* __restrict__ col_pos,
    u16* __restrict__ feat)             // [N, 576] bf16 (544 used)
{
    __shared__ float sLog[2][2][8][8];  // [node][wave][head][edge]  2 KB
    __shared__ float sY[2][512];        // partial y exchange        4 KB
    __shared__ float sV[2][8][4];       // dx,dy,dz,aid per head     256 B

    const int wave4 = threadIdx.x >> 6;   // 0..3
    const int nb = wave4 >> 1;            // node within block
    const int w  = wave4 & 1;             // wave within node
    const int lane = threadIdx.x & 63;
    const int n = blockIdx.x * 2 + nb;
    const int h = lane >> 3;
    const int sub = lane & 7;
    const int hoff = lane * 8;            // == h*64 + sub*8

    const size_t qbase = (size_t)n * QKV_W;

    // q fragment (8 dims), fp32
    float qf[8];
    {
        const us8 qu = *(const us8*)(qkv + qbase + hoff);
        #pragma unroll
        for (int i = 0; i < 8; ++i) qf[i] = bf2f(qu[i]);
    }
    // qv (3 per head) via wave shuffle from the 24 bf16 at col 1536
    float qv0, qv1, qv2;
    {
        const float qvl = bf2f(qkv[qbase + 1536 + (lane < 24 ? lane : 0)]);
        qv0 = __shfl(qvl, h * 3 + 0);
        qv1 = __shfl(qvl, h * 3 + 1);
        qv2 = __shfl(qvl, h * 3 + 2);
    }
    const float px = pos[3 * n + 0], py = pos[3 * n + 1], pz = pos[3 * n + 2];

    // per-edge metadata for THIS wave's 8 edges, held in lanes 0..7
    // (all 8-lane groups hold duplicates)
    const int j8 = lane & 7;
    const int e0 = n * DEG + w * 8 + j8;
    const int c_l  = col_index[e0];
    const int cc_l = to_col[c_l];
    const float d_l = dist[e0];
    const float invd_l = (d_l == 0.f) ? 0.f : (1.f / d_l);
    const float rx_l = col_pos[3 * c_l + 0] - px;
    const float ry_l = col_pos[3 * c_l + 1] - py;
    const float rz_l = col_pos[3 * c_l + 2] - pz;

    // bias: lane (h,sub) holds bias for head h, edge w*8+sub
    const float b_own = att_bias[(size_t)h * E_EDGES + n * DEG + w * 8 + sub];

    // ---- pass 1: logits for my 8 edges -------------------------------------
    float logit[8];
    #pragma unroll
    for (int j = 0; j < 8; ++j) {
        const int cc = __shfl(cc_l, j);
        const us8 ku = *(const us8*)(qkv + (size_t)cc * QKV_W + 512 + hoff);
        float dot = 0.f;
        #pragma unroll
        for (int i = 0; i < 8; ++i) dot += qf[i] * bf2f(ku[i]);
        dot += __shfl_xor(dot, 1, 8);
        dot += __shfl_xor(dot, 2, 8);
        dot += __shfl_xor(dot, 4, 8);
        const float invd = __shfl(invd_l, j);
        const float ang = qv0 * __shfl(rx_l, j) + qv1 * __shfl(ry_l, j)
                        + qv2 * __shfl(rz_l, j);
        const float bj = __shfl(b_own, j, 8);   // lane h*8+j of this group
        logit[j] = dot + bj + ang * invd;
    }

    // ---- exchange logits, softmax over all 16 ------------------------------
    if (sub == 0) {
        #pragma unroll
        for (int j = 0; j < 8; ++j) sLog[nb][w][h][j] = logit[j];
    }
    __syncthreads();
    float lo[8];
    #pragma unroll
    for (int j = 0; j < 8; ++j) lo[j] = sLog[nb][1 - w][h][j];

    float m = logit[0];
    #pragma unroll
    for (int j = 1; j < 8; ++j) m = fmaxf(m, logit[j]);
    #pragma unroll
    for (int j = 0; j < 8; ++j) m = fmaxf(m, lo[j]);
    float s = 0.f;
    #pragma unroll
    for (int j = 0; j < 8; ++j) { logit[j] = __expf(logit[j] - m); s += logit[j]; }
    #pragma unroll
    for (int j = 0; j < 8; ++j) s += __expf(lo[j] - m);
    const float inv_s = 1.f / s;

    // ---- pass 2: weighted accumulation over my 8 edges ---------------------
    float y[8] = {0.f, 0.f, 0.f, 0.f, 0.f, 0.f, 0.f, 0.f};
    float dx = 0.f, dy = 0.f, dz = 0.f, aid = 0.f;
    #pragma unroll
    for (int j = 0; j < 8; ++j) {
        const float a = logit[j] * inv_s;
        const int cc = __shfl(cc_l, j);
        const us8 vu = *(const us8*)(qkv + (size_t)cc * QKV_W + 1024 + hoff);
        #pragma unroll
        for (int i = 0; i < 8; ++i) y[i] += a * bf2f(vu[i]);
        const float na = a * __shfl(invd_l, j);
        dx += na * __shfl(rx_l, j);      // dst_vec - src_vec == sum na*rel
        dy += na * __shfl(ry_l, j);
        dz += na * __shfl(rz_l, j);
        aid += na;
    }

    // ---- combine the two waves' partials -----------------------------------
    if (w == 0) {
        #pragma unroll
        for (int i = 0; i < 8; ++i) sY[nb][hoff + i] = y[i];
        if (sub == 0) {
            sV[nb][h][0] = dx; sV[nb][h][1] = dy;
            sV[nb][h][2] = dz; sV[nb][h][3] = aid;
        }
    }
    __syncthreads();
    if (w == 1) {
        #pragma unroll
        for (int i = 0; i < 8; ++i) y[i] += sY[nb][hoff + i];

        u16* f = feat + (size_t)n * FEAT_W + h * 68;
        ushort4 o0, o1;
        o0.x = f2bf(y[0]); o0.y = f2bf(y[1]); o0.z = f2bf(y[2]); o0.w = f2bf(y[3]);
        o1.x = f2bf(y[4]); o1.y = f2bf(y[5]); o1.z = f2bf(y[6]); o1.w = f2bf(y[7]);
        *(ushort4*)(f + sub * 8 + 0) = o0;
        *(ushort4*)(f + sub * 8 + 4) = o1;
        if (sub == 0) {
            dx += sV[nb][h][0]; dy += sV[nb][h][1];
            dz += sV[nb][h][2]; aid += sV[nb][h][3];
            const float nrm = sqrtf(dx * dx + dy * dy + dz * dz);
            const float rn = 1.f / fmaxf(nrm, 1e-12f);
            ushort4 ex;
            ex.x = f2bf(dx * rn); ex.y = f2bf(dy * rn);
            ex.z = f2bf(dz * rn); ex.w = f2bf(aid);
            *(ushort4*)(f + 64) = ex;
        }
    }
}

// ---------------------------------------------------------------------------
extern "C" void kernel_launch(void* const* d_in, const int* in_sizes, int n_in,
                              void* d_out, int out_size, void* d_ws, size_t ws_size,
                              hipStream_t stream)
{
    const float* x         = (const float*)d_in[0];
    const int*   col_index = (const int*)d_in[2];
    const int*   to_col    = (const int*)d_in[3];
    const float* att_bias  = (const float*)d_in[4];
    const float* dist      = (const float*)d_in[5];
    const float* pos       = (const float*)d_in[6];
    const float* col_pos   = (const float*)d_in[7];
    const float* Wq        = (const float*)d_in[8];
    const float* Wqv       = (const float*)d_in[9];
    const float* Wk        = (const float*)d_in[10];
    const float* Wv        = (const float*)d_in[11];
    const float* Wout      = (const float*)d_in[12];
    const float* bout      = (const float*)d_in[13];
    float* out = (float*)d_out;

    // Workspace layout (bytes), total ~47.5 MB
    char* ws = (char*)d_ws;
    u16* qkv   = (u16*)(ws + 0);           // [8192,1664] bf16  27,262,976
    u16* xh    = (u16*)(ws + 27262976);    // [8192,512]  bf16   8,388,608
    u16* Bfuse = (u16*)(ws + 35651584);    // [1792,512]  bf16   1,835,008
    u16* Woth  = (u16*)(ws + 37486592);    // [512,576]   bf16     589,824
    u16* feat  = (u16*)(ws + 38076416);    // [8192,576]  bf16   9,437,184

    dim3 blk(256);

    // 0) prep: x->bf16, Bfuse (incl. qv rows + zero pad to 1792), Woth
    hipLaunchKernelGGL(prep_kernel, dim3(5280), blk, 0, stream,
                       x, Wq, Wk, Wv, Wqv, Wout, xh, Bfuse, Woth);

    // 1) qkv = xh * Bfuse^T  (1600 blocks, pinned reg-B streaming)
    hipLaunchKernelGGL(gemm_qkv, dim3(1600), blk, 0, stream, xh, Bfuse, qkv);

    // 2) edge: 2 waves per node, LDS logit/partial exchange
    hipLaunchKernelGGL(edge_kernel, dim3(N_NODES / 2), blk, 0, stream,
                       qkv, col_index, to_col, att_bias, dist, pos, col_pos, feat);

    // 3) out = feat * Woth^T + bout  (64x128 tiles, grid 512 = 2/CU)
    hipLaunchKernelGGL(gemm_out, dim3(512), blk, 0, stream,
                       feat, Woth, bout, out);
}

// Round 5
// 161.666 us; speedup vs baseline: 1.6230x; 1.5583x over previous
//
#include <hip/hip_runtime.h>
#include <math.h>

#define N_NODES 8192
#define D_FEAT  512
#define DEG     16
#define E_EDGES (N_NODES * DEG)
#define FEAT_W  576      // 544 used (8*(64+4)) + 32 zero-pad for K%64==0
#define FEAT_USED 544
#define OUT_W   512
#define QKV_W   1664     // 512 q | 512 k | 512 v | 24 qv | 104 pad  (13*128)

typedef unsigned short u16;
typedef __attribute__((ext_vector_type(8))) short short8;   // 8 bf16 for MFMA
typedef __attribute__((ext_vector_type(8))) unsigned short us8;
typedef __attribute__((ext_vector_type(4))) float f32x4;

// ---- bf16 helpers (RNE) ----------------------------------------------------
__device__ __forceinline__ u16 f2bf(float f) {
    union { float f; unsigned u; } c; c.f = f;
    unsigned u = c.u;
    unsigned r = u + 0x7FFFu + ((u >> 16) & 1u);
    return (u16)(r >> 16);
}
__device__ __forceinline__ float bf2f(u16 h) {
    union { unsigned u; float f; } c; c.u = ((unsigned)h) << 16;
    return c.f;
}

// ---- async global->LDS 16B (lds dest = wave-uniform base + lane*16) --------
__device__ __forceinline__ void async16(const void* g, void* l) {
    __builtin_amdgcn_global_load_lds(
        (const __attribute__((address_space(1))) void*)g,
        (__attribute__((address_space(3))) void*)l, 16, 0, 0);
}

// ---------------------------------------------------------------------------
// qkv GEMM: qkv[8192,1664] = xh[8192,512] * Bfuse[1664,512]^T, bf16 in/out.
// BK=64, 128x128 tiles, 4 waves, grid 832 = 64 Mtiles x 13 Ntiles,
// XCD-swizzled. R7/R11-proven main loop (round-0 baseline, 163.9us total).
// ROUND-4 CHANGE (only): epilogue stages the C-tile in the now-free 32 KB
// LDS and writes 256 B contiguous per row (full 128 B lines). Round-1
// counters showed the old scattered 32 B-chunk epilogue wrote 62 MB to HBM
// for a 27 MB output (2.3x partial-line amplification, RMW at ~1.5 TB/s
// effective) -- that was the dominant cost of this kernel.
// ---------------------------------------------------------------------------
__global__ __launch_bounds__(256) void gemm_qkv(
    const u16* __restrict__ xh, const u16* __restrict__ Bfuse,
    u16* __restrict__ qkv)
{
    __shared__ u16 smem[128 * 64 * 2];   // 32 KB
    u16* sA = smem;
    u16* sB = smem + 128 * 64;

    const int tid = threadIdx.x;
    const int flat = blockIdx.x;
    const int xcd = flat & 7;
    const int rr  = flat >> 3;                  // 0..103
    const int bm  = (xcd + 8 * (rr / 13)) * 128;
    const int bn  = (rr % 13) * 128;

    const int wave = tid >> 6;
    const int lane = tid & 63;
    const int wr   = (wave >> 1) * 64;
    const int wc   = (wave & 1) * 64;
    const int lrow = lane & 15;
    const int quad = lane >> 4;

    f32x4 acc[4][4];
    #pragma unroll
    for (int i = 0; i < 4; ++i)
        #pragma unroll
        for (int j = 0; j < 4; ++j) {
            f32x4 z = {0.f, 0.f, 0.f, 0.f};
            acc[i][j] = z;
        }

    for (int k0 = 0; k0 < 512; k0 += 64) {
        #pragma unroll
        for (int i = 0; i < 4; ++i) {
            const int lin = i * 256 + tid;            // 1024 chunks/matrix
            const int row = lin >> 3;
            const int seg = ((lin & 7) ^ (row & 7)) << 3;
            async16(xh    + (size_t)(bm + row) * 512 + k0 + seg, sA + (lin << 3));
            async16(Bfuse + (size_t)(bn + row) * 512 + k0 + seg, sB + (lin << 3));
        }
        __syncthreads();

        #pragma unroll
        for (int ko = 0; ko < 64; ko += 32) {
            const int cbase = ko >> 3;
            short8 a_h[4], b_h[4];
            #pragma unroll
            for (int t = 0; t < 4; ++t) {
                const int ra = wr + t * 16 + lrow;
                const int rb = wc + t * 16 + lrow;
                a_h[t] = *(const short8*)&sA[ra * 64 + (((cbase + quad) ^ (ra & 7)) << 3)];
                b_h[t] = *(const short8*)&sB[rb * 64 + (((cbase + quad) ^ (rb & 7)) << 3)];
            }
            #pragma unroll
            for (int mt = 0; mt < 4; ++mt)
                #pragma unroll
                for (int nt = 0; nt < 4; ++nt)
                    acc[mt][nt] = __builtin_amdgcn_mfma_f32_16x16x32_bf16(
                        a_h[mt], b_h[nt], acc[mt][nt], 0, 0, 0);
        }
        __syncthreads();
    }

    // ---- epilogue: LDS-staged coalesced C write ----------------------------
    // C/D layout: col = lane&15, row = quad*4 + r. Stage into sC[128][128]
    // (reuses the 32 KB staging LDS, now idle), then each thread writes 16 B
    // chunks; 16 threads/row -> 256 B contiguous per row = full HBM lines.
    u16* sC = smem;
    #pragma unroll
    for (int nt = 0; nt < 4; ++nt) {
        const int col = wc + nt * 16 + lrow;
        #pragma unroll
        for (int mt = 0; mt < 4; ++mt)
            #pragma unroll
            for (int r = 0; r < 4; ++r) {
                const int row = wr + mt * 16 + quad * 4 + r;
                sC[row * 128 + col] = f2bf(acc[mt][nt][r]);
            }
    }
    __syncthreads();
    #pragma unroll
    for (int p = 0; p < 8; ++p) {
        const int lin = p * 256 + tid;       // 0..2047 chunks of 16 B
        const int row = lin >> 4;            // 0..127
        const int c16 = lin & 15;
        *(uint4*)(qkv + (size_t)(bm + row) * QKV_W + bn + c16 * 8) =
            *(const uint4*)&sC[row * 128 + c16 * 8];
    }
}

// ---------------------------------------------------------------------------
// Out GEMM: out[8192,512] = feat[8192,576] * Woth[512,576]^T + bout.
// 64x128 tiles, BK=64, grid 512 = 2 blocks/CU. R11-proven.
// ---------------------------------------------------------------------------
__global__ __launch_bounds__(256) void gemm_out(
    const u16* __restrict__ feat, const u16* __restrict__ Woth,
    const float* __restrict__ bout, float* __restrict__ out)
{
    __shared__ u16 smem[64 * 64 + 128 * 64];   // 24 KB
    u16* sA = smem;
    u16* sB = smem + 64 * 64;

    const int tid = threadIdx.x;
    const int flat = blockIdx.x;
    const int xcd = flat & 7;
    const int rr  = flat >> 3;                  // 0..63
    const int bm  = (xcd + 8 * (rr / 4)) * 64;
    const int bn  = (rr % 4) * 128;

    const int wave = tid >> 6;
    const int lane = tid & 63;
    const int wr   = (wave >> 1) * 32;
    const int wc   = (wave & 1) * 64;
    const int lrow = lane & 15;
    const int quad = lane >> 4;

    f32x4 acc[2][4];
    #pragma unroll
    for (int i = 0; i < 2; ++i)
        #pragma unroll
        for (int j = 0; j < 4; ++j) {
            f32x4 z = {0.f, 0.f, 0.f, 0.f};
            acc[i][j] = z;
        }

    for (int k0 = 0; k0 < FEAT_W; k0 += 64) {
        #pragma unroll
        for (int i = 0; i < 2; ++i) {             // A: 512 chunks
            const int lin = i * 256 + tid;
            const int row = lin >> 3;
            const int seg = ((lin & 7) ^ (row & 7)) << 3;
            async16(feat + (size_t)(bm + row) * FEAT_W + k0 + seg, sA + (lin << 3));
        }
        #pragma unroll
        for (int i = 0; i < 4; ++i) {             // B: 1024 chunks
            const int lin = i * 256 + tid;
            const int row = lin >> 3;
            const int seg = ((lin & 7) ^ (row & 7)) << 3;
            async16(Woth + (size_t)(bn + row) * FEAT_W + k0 + seg, sB + (lin << 3));
        }
        __syncthreads();

        #pragma unroll
        for (int ko = 0; ko < 64; ko += 32) {
            const int cbase = ko >> 3;
            short8 a_h[2], b_h[4];
            #pragma unroll
            for (int t = 0; t < 2; ++t) {
                const int ra = wr + t * 16 + lrow;
                a_h[t] = *(const short8*)&sA[ra * 64 + (((cbase + quad) ^ (ra & 7)) << 3)];
            }
            #pragma unroll
            for (int t = 0; t < 4; ++t) {
                const int rb = wc + t * 16 + lrow;
                b_h[t] = *(const short8*)&sB[rb * 64 + (((cbase + quad) ^ (rb & 7)) << 3)];
            }
            #pragma unroll
            for (int mt = 0; mt < 2; ++mt)
                #pragma unroll
                for (int nt = 0; nt < 4; ++nt)
                    acc[mt][nt] = __builtin_amdgcn_mfma_f32_16x16x32_bf16(
                        a_h[mt], b_h[nt], acc[mt][nt], 0, 0, 0);
        }
        __syncthreads();
    }

    #pragma unroll
    for (int nt = 0; nt < 4; ++nt) {
        const int col = bn + wc + nt * 16 + lrow;
        const float bb = bout[col];
        #pragma unroll
        for (int mt = 0; mt < 2; ++mt)
            #pragma unroll
            for (int r = 0; r < 4; ++r) {
                const int row = bm + wr + mt * 16 + quad * 4 + r;
                out[(size_t)row * OUT_W + col] = acc[mt][nt][r] + bb;
            }
    }
}

// ---------------------------------------------------------------------------
// Fused prep (R7/R11-proven): block-range partition over three jobs.
// ---------------------------------------------------------------------------
__global__ __launch_bounds__(256) void prep_kernel(
    const float* __restrict__ x,
    const float* __restrict__ Wq, const float* __restrict__ Wk,
    const float* __restrict__ Wv, const float* __restrict__ Wqv,
    const float* __restrict__ Wout,
    u16* __restrict__ xh, u16* __restrict__ B, u16* __restrict__ Woth)
{
    const int b = blockIdx.x;
    const int tid = threadIdx.x;
    if (b < 4096) {
        const int i = b * 256 + tid;
        const float4 v = ((const float4*)x)[i];
        ushort4 h;
        h.x = f2bf(v.x); h.y = f2bf(v.y); h.z = f2bf(v.z); h.w = f2bf(v.w);
        ((ushort4*)xh)[i] = h;
    } else if (b < 4928) {
        const int idx = (b - 4096) * 256 + tid;      // < 212992
        const int row = idx >> 7;                    // 0..1663
        const int c4  = idx & 127;
        float4 v = make_float4(0.f, 0.f, 0.f, 0.f);
        float scale = 1.f;
        if (row < 512) {
            v = *(const float4*)(Wq + (size_t)row * 512 + c4 * 4);
            scale = 0.125f;                          // 1/sqrt(64) folded into Wq
        } else if (row < 1024) {
            v = *(const float4*)(Wk + (size_t)(row - 512) * 512 + c4 * 4);
        } else if (row < 1536) {
            v = *(const float4*)(Wv + (size_t)(row - 1024) * 512 + c4 * 4);
        } else if (row < 1560) {
            v = *(const float4*)(Wqv + (size_t)(row - 1536) * 512 + c4 * 4);
        }
        ushort4 h;
        h.x = f2bf(v.x * scale); h.y = f2bf(v.y * scale);
        h.z = f2bf(v.z * scale); h.w = f2bf(v.w * scale);
        ((ushort4*)B)[idx] = h;
    } else {
        const int i = (b - 4928) * 256 + tid;        // < 73728 exact
        const int row = i / (FEAT_W / 4);            // /144
        const int c4  = i % (FEAT_W / 4);
        float4 v = make_float4(0.f, 0.f, 0.f, 0.f);
        if (c4 < FEAT_USED / 4)
            v = *(const float4*)(Wout + (size_t)row * FEAT_USED + c4 * 4);
        ushort4 h;
        h.x = f2bf(v.x); h.y = f2bf(v.y); h.z = f2bf(v.z); h.w = f2bf(v.w);
        ((ushort4*)Woth)[i] = h;
    }
}

// ---------------------------------------------------------------------------
// Edge stage: TWO WAVES PER NODE (wave owns 8 edges, all 512 dims).
// Block = 256 threads = 4 waves = 2 nodes. lane = h*8+sub; hoff = lane*8.
// Pass 1: each wave computes 8 logits (coalesced k-row gathers).
// LDS exchange of per-head logits (64 fp32/node) -> full 16-way softmax
// replicated in both waves. Pass 2: each wave re-gathers its 8 v rows and
// accumulates partial y/dx/dy/dz/aid; wave 0 publishes partials via LDS;
// wave 1 combines and writes feat. ~6 KB LDS/block -> occupancy VGPR-bound.
// ---------------------------------------------------------------------------
__global__ __launch_bounds__(256) void edge_kernel(
    const u16* __restrict__ qkv,        // [N, 1664] bf16
    const int* __restrict__ col_index, const int* __restrict__ to_col,
    const float* __restrict__ att_bias, const float* __restrict__ dist,
    const float* __restrict__ pos, const float* __restrict__ col_pos,
    u16* __restrict__ feat)             // [N, 576] bf16 (544 used)
{
    __shared__ float sLog[2][2][8][8];  // [node][wave][head][edge]  2 KB
    __shared__ float sY[2][512];        // partial y exchange        4 KB
    __shared__ float sV[2][8][4];       // dx,dy,dz,aid per head     256 B

    const int wave4 = threadIdx.x >> 6;   // 0..3
    const int nb = wave4 >> 1;            // node within block
    const int w  = wave4 & 1;             // wave within node
    const int lane = threadIdx.x & 63;
    const int n = blockIdx.x * 2 + nb;
    const int h = lane >> 3;
    const int sub = lane & 7;
    const int hoff = lane * 8;            // == h*64 + sub*8

    const size_t qbase = (size_t)n * QKV_W;

    // q fragment (8 dims), fp32
    float qf[8];
    {
        const us8 qu = *(const us8*)(qkv + qbase + hoff);
        #pragma unroll
        for (int i = 0; i < 8; ++i) qf[i] = bf2f(qu[i]);
    }
    // qv (3 per head) via wave shuffle from the 24 bf16 at col 1536
    float qv0, qv1, qv2;
    {
        const float qvl = bf2f(qkv[qbase + 1536 + (lane < 24 ? lane : 0)]);
        qv0 = __shfl(qvl, h * 3 + 0);
        qv1 = __shfl(qvl, h * 3 + 1);
        qv2 = __shfl(qvl, h * 3 + 2);
    }
    const float px = pos[3 * n + 0], py = pos[3 * n + 1], pz = pos[3 * n + 2];

    // per-edge metadata for THIS wave's 8 edges, held in lanes 0..7
    // (all 8-lane groups hold duplicates)
    const int j8 = lane & 7;
    const int e0 = n * DEG + w * 8 + j8;
    const int c_l  = col_index[e0];
    const int cc_l = to_col[c_l];
    const float d_l = dist[e0];
    const float invd_l = (d_l == 0.f) ? 0.f : (1.f / d_l);
    const float rx_l = col_pos[3 * c_l + 0] - px;
    const float ry_l = col_pos[3 * c_l + 1] - py;
    const float rz_l = col_pos[3 * c_l + 2] - pz;

    // bias: lane (h,sub) holds bias for head h, edge w*8+sub
    const float b_own = att_bias[(size_t)h * E_EDGES + n * DEG + w * 8 + sub];

    // ---- pass 1: logits for my 8 edges -------------------------------------
    float logit[8];
    #pragma unroll
    for (int j = 0; j < 8; ++j) {
        const int cc = __shfl(cc_l, j);
        const us8 ku = *(const us8*)(qkv + (size_t)cc * QKV_W + 512 + hoff);
        float dot = 0.f;
        #pragma unroll
        for (int i = 0; i < 8; ++i) dot += qf[i] * bf2f(ku[i]);
        dot += __shfl_xor(dot, 1, 8);
        dot += __shfl_xor(dot, 2, 8);
        dot += __shfl_xor(dot, 4, 8);
        const float invd = __shfl(invd_l, j);
        const float ang = qv0 * __shfl(rx_l, j) + qv1 * __shfl(ry_l, j)
                        + qv2 * __shfl(rz_l, j);
        const float bj = __shfl(b_own, j, 8);   // lane h*8+j of this group
        logit[j] = dot + bj + ang * invd;
    }

    // ---- exchange logits, softmax over all 16 ------------------------------
    if (sub == 0) {
        #pragma unroll
        for (int j = 0; j < 8; ++j) sLog[nb][w][h][j] = logit[j];
    }
    __syncthreads();
    float lo[8];
    #pragma unroll
    for (int j = 0; j < 8; ++j) lo[j] = sLog[nb][1 - w][h][j];

    float m = logit[0];
    #pragma unroll
    for (int j = 1; j < 8; ++j) m = fmaxf(m, logit[j]);
    #pragma unroll
    for (int j = 0; j < 8; ++j) m = fmaxf(m, lo[j]);
    float s = 0.f;
    #pragma unroll
    for (int j = 0; j < 8; ++j) { logit[j] = __expf(logit[j] - m); s += logit[j]; }
    #pragma unroll
    for (int j = 0; j < 8; ++j) s += __expf(lo[j] - m);
    const float inv_s = 1.f / s;

    // ---- pass 2: weighted accumulation over my 8 edges ---------------------
    float y[8] = {0.f, 0.f, 0.f, 0.f, 0.f, 0.f, 0.f, 0.f};
    float dx = 0.f, dy = 0.f, dz = 0.f, aid = 0.f;
    #pragma unroll
    for (int j = 0; j < 8; ++j) {
        const float a = logit[j] * inv_s;
        const int cc = __shfl(cc_l, j);
        const us8 vu = *(const us8*)(qkv + (size_t)cc * QKV_W + 1024 + hoff);
        #pragma unroll
        for (int i = 0; i < 8; ++i) y[i] += a * bf2f(vu[i]);
        const float na = a * __shfl(invd_l, j);
        dx += na * __shfl(rx_l, j);      // dst_vec - src_vec == sum na*rel
        dy += na * __shfl(ry_l, j);
        dz += na * __shfl(rz_l, j);
        aid += na;
    }

    // ---- combine the two waves' partials -----------------------------------
    if (w == 0) {
        #pragma unroll
        for (int i = 0; i < 8; ++i) sY[nb][hoff + i] = y[i];
        if (sub == 0) {
            sV[nb][h][0] = dx; sV[nb][h][1] = dy;
            sV[nb][h][2] = dz; sV[nb][h][3] = aid;
        }
    }
    __syncthreads();
    if (w == 1) {
        #pragma unroll
        for (int i = 0; i < 8; ++i) y[i] += sY[nb][hoff + i];

        u16* f = feat + (size_t)n * FEAT_W + h * 68;
        ushort4 o0, o1;
        o0.x = f2bf(y[0]); o0.y = f2bf(y[1]); o0.z = f2bf(y[2]); o0.w = f2bf(y[3]);
        o1.x = f2bf(y[4]); o1.y = f2bf(y[5]); o1.z = f2bf(y[6]); o1.w = f2bf(y[7]);
        *(ushort4*)(f + sub * 8 + 0) = o0;
        *(ushort4*)(f + sub * 8 + 4) = o1;
        if (sub == 0) {
            dx += sV[nb][h][0]; dy += sV[nb][h][1];
            dz += sV[nb][h][2]; aid += sV[nb][h][3];
            const float nrm = sqrtf(dx * dx + dy * dy + dz * dz);
            const float rn = 1.f / fmaxf(nrm, 1e-12f);
            ushort4 ex;
            ex.x = f2bf(dx * rn); ex.y = f2bf(dy * rn);
            ex.z = f2bf(dz * rn); ex.w = f2bf(aid);
            *(ushort4*)(f + 64) = ex;
        }
    }
}

// ---------------------------------------------------------------------------
extern "C" void kernel_launch(void* const* d_in, const int* in_sizes, int n_in,
                              void* d_out, int out_size, void* d_ws, size_t ws_size,
                              hipStream_t stream)
{
    const float* x         = (const float*)d_in[0];
    const int*   col_index = (const int*)d_in[2];
    const int*   to_col    = (const int*)d_in[3];
    const float* att_bias  = (const float*)d_in[4];
    const float* dist      = (const float*)d_in[5];
    const float* pos       = (const float*)d_in[6];
    const float* col_pos   = (const float*)d_in[7];
    const float* Wq        = (const float*)d_in[8];
    const float* Wqv       = (const float*)d_in[9];
    const float* Wk        = (const float*)d_in[10];
    const float* Wv        = (const float*)d_in[11];
    const float* Wout      = (const float*)d_in[12];
    const float* bout      = (const float*)d_in[13];
    float* out = (float*)d_out;

    // Workspace layout (bytes), total ~47.4 MB
    char* ws = (char*)d_ws;
    u16* qkv   = (u16*)(ws + 0);           // [8192,1664] bf16  27,262,976
    u16* xh    = (u16*)(ws + 27262976);    // [8192,512]  bf16   8,388,608
    u16* Bfuse = (u16*)(ws + 35651584);    // [1664,512]  bf16   1,703,936
    u16* Woth  = (u16*)(ws + 37355520);    // [512,576]   bf16     589,824
    u16* feat  = (u16*)(ws + 37945344);    // [8192,576]  bf16   9,437,184

    dim3 blk(256);

    // 0) prep: x->bf16, Bfuse (incl. qv rows), Woth
    hipLaunchKernelGGL(prep_kernel, dim3(5216), blk, 0, stream,
                       x, Wq, Wk, Wv, Wqv, Wout, xh, Bfuse, Woth);

    // 1) qkv = xh * Bfuse^T  (832 blocks, XCD-swizzled, coalesced C-write)
    hipLaunchKernelGGL(gemm_qkv, dim3(832), blk, 0, stream, xh, Bfuse, qkv);

    // 2) edge: 2 waves per node, LDS logit/partial exchange
    hipLaunchKernelGGL(edge_kernel, dim3(N_NODES / 2), blk, 0, stream,
                       qkv, col_index, to_col, att_bias, dist, pos, col_pos, feat);

    // 3) out = feat * Woth^T + bout  (64x128 tiles, grid 512 = 2/CU)
    hipLaunchKernelGGL(gemm_out, dim3(512), blk, 0, stream,
                       feat, Woth, bout, out);
}